// Round 6
// baseline (2677.943 us; speedup 1.0000x reference)
//
#include <hip/hip_runtime.h>

#define Bsz 128
#define Lseq 512
#define Hdim 256
#define Tn 16
#define START_TAG 14
#define END_TAG 15

typedef float f32x4 __attribute__((ext_vector_type(4)));
typedef short s16x8 __attribute__((ext_vector_type(8)));

__device__ __forceinline__ unsigned short f2bf(float f) {
    unsigned int u = __builtin_bit_cast(unsigned int, f);
    u += 0x7fffu + ((u >> 16) & 1u);          // RNE
    return (unsigned short)(u >> 16);
}
__device__ __forceinline__ float bf2f(unsigned int bits16) {
    return __builtin_bit_cast(float, bits16 << 16);
}
__device__ __forceinline__ float sigmoidf_(float x) {
    return 1.0f / (1.0f + __expf(-x));
}

// emb fp32 [V*256] -> packed bf16 pairs [V*128]
__global__ void embprep_kernel(const float* __restrict__ emb,
                               unsigned int* __restrict__ embb, int n2) {
    int i = blockIdx.x * blockDim.x + threadIdx.x;
    int stride = gridDim.x * blockDim.x;
    for (; i < n2; i += stride)
        embb[i] = (unsigned int)f2bf(emb[2 * i]) | ((unsigned int)f2bf(emb[2 * i + 1]) << 16);
}

// wtile[dir][ug(16)][wv(4)][ki(16)][lane(64)][4 uints] : MFMA B-frag order.
// lane l: n=l&15, kq=l>>4; col(n,wv) = (n&3)*256 + ug*16 + wv*4 + (n>>2)
// (gate in n's low 2 bits -> all 4 gates of a unit live in adjacent lanes).
__global__ void wprep_kernel(const float* __restrict__ wih_f, const float* __restrict__ whh_f,
                             const float* __restrict__ wih_b, const float* __restrict__ whh_b,
                             unsigned int* __restrict__ wtile) {
    int bid = blockIdx.x;                 // ((dir*16+ug)*4+wv)*16+ki
    int ki  = bid & 15;
    int wv  = (bid >> 4) & 3;
    int ug  = (bid >> 6) & 15;
    int dir = bid >> 10;
    int t = threadIdx.x;                  // 256 = lane(64) x j(4)
    int lane = t >> 2, j = t & 3;
    int n = lane & 15, kq = lane >> 4;
    int k0 = ki * 32 + kq * 8 + 2 * j;
    int col = (n & 3) * 256 + ug * 16 + wv * 4 + (n >> 2);
    const float* wih = dir ? wih_b : wih_f;
    const float* whh = dir ? whh_b : whh_f;
    float f0, f1;
    if (k0 < 256) { f0 = wih[col * 256 + k0];       f1 = wih[col * 256 + k0 + 1]; }
    else          { f0 = whh[col * 256 + k0 - 256]; f1 = whh[col * 256 + k0 - 255]; }
    wtile[(size_t)bid * 256 + t] = (unsigned int)f2bf(f0) | ((unsigned int)f2bf(f1) << 16);
}

__global__ void lengths_kernel(const int* __restrict__ tag, int* __restrict__ lengths) {
    int b = blockIdx.x;
    int tid = threadIdx.x;
    int cnt = 0;
    for (int l = tid; l < Lseq; l += blockDim.x)
        cnt += (tag[b * Lseq + l] != 0) ? 1 : 0;
    for (int off = 32; off > 0; off >>= 1) cnt += __shfl_down(cnt, off);
    __shared__ int red[4];
    if ((tid & 63) == 0) red[tid >> 6] = cnt;
    __syncthreads();
    if (tid == 0) lengths[b] = red[0] + red[1] + red[2] + red[3];
}

// Persistent BiLSTM, 256 WGs (1/CU). WG = dir(2) x bg(8: 16 batches) x ug(16: 16 units).
// No flags, no group barrier: h words carry an epoch tag in the bf16 LSBs
// (parity (s>>1)&1, ring depth 2). Readers spin per-word until tag matches.
// Wave-local cell update (gate in lane low bits) -> single __syncthreads/step.
// Weights live in VGPRs. x-half MFMAs for s+1 run after the h store (overlap).
__global__ __launch_bounds__(256, 1) void bilstm_persist(
    const int* __restrict__ bd,
    const unsigned int* __restrict__ embb,     // [V][128]
    const unsigned int* __restrict__ wtile,    // frag-ordered weights
    const float* __restrict__ b_f, const float* __restrict__ b_b,
    const float* __restrict__ w_cls,
    float* __restrict__ em_f, float* __restrict__ em_b,
    unsigned int* __restrict__ ring)           // [2 dir][2 slot][128 b][128 uints]
{
    const int wg  = blockIdx.x;
    const int dir = wg >> 7;
    const int bg  = (wg >> 4) & 7;
    const int ug  = wg & 15;
    const int tid = threadIdx.x;
    const int gb0 = bg * 16;

    __shared__ unsigned int h_lds[2][16 * 132];   // double-buffered staged h
    __shared__ float wcls_lds[256];

    wcls_lds[tid] = w_cls[(size_t)ug * (2 * Hdim) + dir * Hdim + tid];

    const int wv = tid >> 6;
    const int l  = tid & 63;
    const int n  = l & 15;
    const int kq = l >> 4;

    // ---- weights into VGPRs (16 x uint4 = 64 regs) ----
    uint4 w_reg[16];
    {
        const unsigned int* wsrc =
            wtile + ((size_t)((dir * 16 + ug) * 4 + wv) * 16) * 256 + l * 4;
        #pragma unroll
        for (int ki = 0; ki < 16; ++ki)
            w_reg[ki] = *(const uint4*)(wsrc + ki * 256);
    }
    const float bias_lane = (dir ? b_b : b_f)[(n & 3) * 256 + ug * 16 + wv * 4 + (n >> 2)];
    float c_reg[4] = {0.f, 0.f, 0.f, 0.f};
    const int* bdr = bd + (size_t)(gb0 + n) * Lseq;
    unsigned int* rb = ring + (size_t)dir * 2 * 16384;
    const bool storer = ((l & 7) == 0);            // n in {0,8}: u_l in {0,2}
    const int store_col = ug * 8 + wv * 2 + ((n >> 2) >> 1);
    float* emout = dir ? em_b : em_f;

    // poll identity: thread stages 8 uints of row m
    const int pm = tid >> 4, pq0 = (tid & 15) * 8;

    __syncthreads();   // wcls ready

    // ---- prologue: acc_x for s=0 ----
    f32x4 acc_x = {0.f, 0.f, 0.f, 0.f};
    {
        const int t0 = dir ? (Lseq - 1) : 0;
        int tok = bdr[t0];
        const unsigned int* xsrc = embb + (size_t)tok * 128 + kq * 4;
        #pragma unroll
        for (int ki = 0; ki < 8; ++ki) {
            s16x8 a = __builtin_bit_cast(s16x8, *(const uint4*)(xsrc + ki * 16));
            acc_x = __builtin_amdgcn_mfma_f32_16x16x32_bf16(
                a, __builtin_bit_cast(s16x8, w_reg[ki]), acc_x, 0, 0, 0);
        }
    }

    for (int s = 0; s < Lseq; ++s) {
        // ---- A: poll-load h_{s-1} (tagged) -> h_lds[s&1] ----
        {
            const unsigned int* src = rb + ((s + 1) & 1) * 16384 + (gb0 + pm) * 128 + pq0;
            const unsigned int want = (((s + 3) >> 1) & 1) * 0x00010001u;
            unsigned int v[8];
            #pragma unroll
            for (int j = 0; j < 8; ++j)
                v[j] = __hip_atomic_load(src + j, __ATOMIC_RELAXED, __HIP_MEMORY_SCOPE_AGENT);
            bool again = true;
            while (again) {
                again = false;
                #pragma unroll
                for (int j = 0; j < 8; ++j)
                    if ((v[j] & 0x00010001u) != want) {
                        v[j] = __hip_atomic_load(src + j, __ATOMIC_RELAXED,
                                                 __HIP_MEMORY_SCOPE_AGENT);
                        again = true;
                    }
            }
            unsigned int* dst = &h_lds[s & 1][pm * 132 + pq0];
            *(uint4*)dst       = make_uint4(v[0], v[1], v[2], v[3]);
            *(uint4*)(dst + 4) = make_uint4(v[4], v[5], v[6], v[7]);
        }
        __syncthreads();
        const unsigned int* hb = &h_lds[s & 1][0];

        // ---- B0 (wave0): emission row j=ug for t_prev from staged h ----
        if (wv == 0 && s > 0) {
            float p = 0.f;
            #pragma unroll
            for (int kih = 0; kih < 8; ++kih) {
                const unsigned int* hp = &hb[n * 132 + kih * 16 + kq * 4];
                const float* wc = &wcls_lds[kih * 32 + kq * 8];
                #pragma unroll
                for (int j = 0; j < 4; ++j) {
                    unsigned int v = hp[j];
                    p += bf2f(v & 0xffffu) * wc[2 * j] + bf2f(v >> 16) * wc[2 * j + 1];
                }
            }
            p += __shfl_xor(p, 16);
            p += __shfl_xor(p, 32);
            if (l < 16) {
                int t_prev = dir ? (Lseq - s) : (s - 1);
                emout[((size_t)(gb0 + l) * Lseq + t_prev) * Tn + ug] = p;
            }
        }

        // ---- B: 8 h-MFMAs on top of acc_x ----
        f32x4 acc = acc_x;
        #pragma unroll
        for (int kih = 0; kih < 8; ++kih) {
            s16x8 a = *(const s16x8*)&hb[n * 132 + kih * 16 + kq * 4];
            acc = __builtin_amdgcn_mfma_f32_16x16x32_bf16(
                a, __builtin_bit_cast(s16x8, w_reg[8 + kih]), acc, 0, 0, 0);
        }

        // ---- C: wave-local cell update + tagged h store ----
        {
            const unsigned int ep = (unsigned int)((s >> 1) & 1);
            const int base = l & ~3;
            unsigned int hbits[4];
            #pragma unroll
            for (int r = 0; r < 4; ++r) {
                float pre = acc[r] + bias_lane;
                float gi = __shfl(pre, base);
                float gf = __shfl(pre, base + 1);
                float gg = __shfl(pre, base + 2);
                float go = __shfl(pre, base + 3);
                float cn = sigmoidf_(gf) * c_reg[r] + sigmoidf_(gi) * tanhf(gg);
                c_reg[r] = cn;
                float hn = sigmoidf_(go) * tanhf(cn);
                hbits[r] = ((unsigned int)f2bf(hn) & 0xFFFEu) | ep;
            }
            unsigned int* dstrow = rb + (s & 1) * 16384;
            #pragma unroll
            for (int r = 0; r < 4; ++r) {
                unsigned int partner = (unsigned int)__shfl((int)hbits[r], l + 4);
                if (storer) {
                    unsigned int pk = hbits[r] | (partner << 16);
                    __hip_atomic_store(dstrow + (gb0 + kq * 4 + r) * 128 + store_col, pk,
                                       __ATOMIC_RELAXED, __HIP_MEMORY_SCOPE_AGENT);
                }
            }
        }

        // ---- E: x-half MFMAs for s+1 (overlaps store flight / peers' compute) ----
        if (s + 1 < Lseq) {
            const int tn = dir ? (Lseq - 2 - s) : (s + 1);
            int tok = bdr[tn];
            const unsigned int* xsrc = embb + (size_t)tok * 128 + kq * 4;
            f32x4 ax = {0.f, 0.f, 0.f, 0.f};
            #pragma unroll
            for (int ki = 0; ki < 8; ++ki) {
                s16x8 a = __builtin_bit_cast(s16x8, *(const uint4*)(xsrc + ki * 16));
                ax = __builtin_amdgcn_mfma_f32_16x16x32_bf16(
                    a, __builtin_bit_cast(s16x8, w_reg[ki]), ax, 0, 0, 0);
            }
            acc_x = ax;
        }
    }

    // ---- tail: emission for h_{L-1} (poll slot 1, epoch of s=511) ----
    {
        const int s = Lseq;                        // formula reuse
        const unsigned int* src = rb + ((s + 1) & 1) * 16384 + (gb0 + pm) * 128 + pq0;
        const unsigned int want = (((s + 3) >> 1) & 1) * 0x00010001u;
        unsigned int v[8];
        #pragma unroll
        for (int j = 0; j < 8; ++j)
            v[j] = __hip_atomic_load(src + j, __ATOMIC_RELAXED, __HIP_MEMORY_SCOPE_AGENT);
        bool again = true;
        while (again) {
            again = false;
            #pragma unroll
            for (int j = 0; j < 8; ++j)
                if ((v[j] & 0x00010001u) != want) {
                    v[j] = __hip_atomic_load(src + j, __ATOMIC_RELAXED,
                                             __HIP_MEMORY_SCOPE_AGENT);
                    again = true;
                }
        }
        unsigned int* dst = &h_lds[0][pm * 132 + pq0];
        *(uint4*)dst       = make_uint4(v[0], v[1], v[2], v[3]);
        *(uint4*)(dst + 4) = make_uint4(v[4], v[5], v[6], v[7]);
        __syncthreads();
        if (wv == 0) {
            const unsigned int* hb = &h_lds[0][0];
            float p = 0.f;
            #pragma unroll
            for (int kih = 0; kih < 8; ++kih) {
                const unsigned int* hp = &hb[n * 132 + kih * 16 + kq * 4];
                const float* wc = &wcls_lds[kih * 32 + kq * 8];
                #pragma unroll
                for (int j = 0; j < 4; ++j) {
                    unsigned int vv = hp[j];
                    p += bf2f(vv & 0xffffu) * wc[2 * j] + bf2f(vv >> 16) * wc[2 * j + 1];
                }
            }
            p += __shfl_xor(p, 16);
            p += __shfl_xor(p, 32);
            if (l < 16) {
                int t_tail = dir ? 0 : (Lseq - 1);
                emout[((size_t)(gb0 + l) * Lseq + t_tail) * Tn + ug] = p;
            }
        }
    }
}

__global__ void golden_kernel(const int* __restrict__ tag,
                              const float* __restrict__ em_f,
                              const float* __restrict__ em_b,
                              const float* __restrict__ b_cls,
                              const float* __restrict__ trans,
                              float* __restrict__ golden)
{
    int b = blockIdx.x;
    int tid = threadIdx.x;
    float s = 0.f;
    for (int l = tid; l < Lseq; l += blockDim.x) {
        int tg = tag[b * Lseq + l];
        if (tg != 0) {
            int prev = (l == 0) ? START_TAG : tag[b * Lseq + l - 1];
            size_t e = ((size_t)b * Lseq + l) * Tn + tg;
            s += em_f[e] + em_b[e] + b_cls[tg] + trans[prev * Tn + tg];
        }
    }
    for (int off = 32; off > 0; off >>= 1) s += __shfl_down(s, off);
    __shared__ float red[4];
    if ((tid & 63) == 0) red[tid >> 6] = s;
    __syncthreads();
    if (tid == 0) atomicAdd(golden, red[0] + red[1] + red[2] + red[3]);
}

__global__ void crf_forward_kernel(const float* __restrict__ em_f,
                                   const float* __restrict__ em_b,
                                   const float* __restrict__ b_cls,
                                   const float* __restrict__ trans,
                                   const int* __restrict__ lengths,
                                   float* __restrict__ allpath)
{
    int b = blockIdx.x;
    int lane = threadIdx.x;
    int j = lane & 15;
    float tcol[16];
    #pragma unroll
    for (int i = 0; i < 16; ++i) tcol[i] = trans[i * Tn + j];
    float bc = b_cls[j];
    size_t e0 = ((size_t)b * Lseq) * Tn + j;
    float alpha = em_f[e0] + em_b[e0] + bc + tcol[START_TAG];
    int len = lengths[b];
    for (int t = 1; t < Lseq; ++t) {
        float av[16];
        float m = -1e30f;
        #pragma unroll
        for (int i = 0; i < 16; ++i) {
            av[i] = __shfl(alpha, i) + tcol[i];
            m = fmaxf(m, av[i]);
        }
        float sum = 0.f;
        #pragma unroll
        for (int i = 0; i < 16; ++i) sum += __expf(av[i] - m);
        size_t e = ((size_t)b * Lseq + t) * Tn + j;
        float nv = em_f[e] + em_b[e] + bc + m + __logf(sum);
        alpha = (t < len) ? nv : alpha;
    }
    if (lane == END_TAG) atomicAdd(allpath, alpha);
}

__global__ void finalize_kernel(const float* __restrict__ scal, float* __restrict__ out) {
    out[0] = (scal[1] - scal[0]) / (float)Bsz;
}

extern "C" void kernel_launch(void* const* d_in, const int* in_sizes, int n_in,
                              void* d_out, int out_size, void* d_ws, size_t ws_size,
                              hipStream_t stream)
{
    (void)in_sizes; (void)n_in; (void)out_size; (void)ws_size;
    const int*   bd     = (const int*)d_in[0];
    const int*   tag    = (const int*)d_in[1];
    const float* emb    = (const float*)d_in[2];
    const float* w_ih_f = (const float*)d_in[3];
    const float* w_hh_f = (const float*)d_in[4];
    const float* b_f    = (const float*)d_in[5];
    const float* w_ih_b = (const float*)d_in[6];
    const float* w_hh_b = (const float*)d_in[7];
    const float* b_b    = (const float*)d_in[8];
    const float* w_cls  = (const float*)d_in[9];
    const float* b_cls  = (const float*)d_in[10];
    const float* trans  = (const float*)d_in[11];
    float* out = (float*)d_out;

    float* ws = (float*)d_ws;
    float* em_f = ws;                                        // 1048576 f
    float* em_b = em_f + (size_t)Bsz * Lseq * Tn;            // 1048576 f
    unsigned int* ring = (unsigned int*)(em_b + (size_t)Bsz * Lseq * Tn);  // 65536 u
    float* scal = (float*)(ring + 65536);                    // 8 f
    int* lengths = (int*)(scal + 8);                         // 128
    unsigned int* wtile = (unsigned int*)(lengths + 128);    // 524288
    unsigned int* embb = wtile + (size_t)524288;             // 30000*128

    // ring pre-fill: bytes 0x01 -> each uint 0x01010101: both bf16 halves are
    // ~3.7e-38 (≈0) with tag LSB=1, matching the s=0 readers' expected epoch.
    hipMemsetAsync(ring, 0x01, (size_t)65536 * 4, stream);
    hipMemsetAsync(scal, 0, 8 * sizeof(float), stream);

    embprep_kernel<<<2048, 256, 0, stream>>>(emb, embb, 30000 * 128);
    wprep_kernel<<<2048, 256, 0, stream>>>(w_ih_f, w_hh_f, w_ih_b, w_hh_b, wtile);
    lengths_kernel<<<Bsz, 256, 0, stream>>>(tag, lengths);

    void* kargs[] = {
        (void*)&bd, (void*)&embb, (void*)&wtile,
        (void*)&b_f, (void*)&b_b, (void*)&w_cls,
        (void*)&em_f, (void*)&em_b, (void*)&ring
    };
    hipLaunchCooperativeKernel((const void*)bilstm_persist,
                               dim3(256), dim3(256), kargs, 0, stream);

    golden_kernel<<<Bsz, 256, 0, stream>>>(tag, em_f, em_b, b_cls, trans, scal);
    crf_forward_kernel<<<Bsz, 64, 0, stream>>>(em_f, em_b, b_cls, trans, lengths, scal + 1);
    finalize_kernel<<<1, 1, 0, stream>>>(scal, out);
}